// Round 1
// baseline (34.768 us; speedup 1.0000x reference)
//
#include <hip/hip_runtime.h>

// Q_s_a[b] = relu(node_emb[idx[b]] * (state[b]·W4)) · W5
//
// Layout: 16 lanes per row; lane j of a group holds elements [4j..4j+3]
// (one float4) of the 64-wide row. A full wave processes 4 consecutive
// rows -> every global load is a coalesced 1 KiB wave access.
__global__ __launch_bounds__(256) void Decoding_43404939493634_kernel(
    const int*   __restrict__ idx,    // [B]
    const float* __restrict__ node,   // [N, 64]
    const float* __restrict__ state,  // [B, 64]
    const float* __restrict__ W4,     // [64]
    const float* __restrict__ W5,     // [64]
    float*       __restrict__ out,    // [B]
    int B)
{
    const int lane16 = threadIdx.x & 15;

    // Weights: 64 floats each, one float4 per lane-of-16. Loaded once.
    const float4 w4 = reinterpret_cast<const float4*>(W4)[lane16];
    const float4 w5 = reinterpret_cast<const float4*>(W5)[lane16];

    const int group   = (blockIdx.x * blockDim.x + threadIdx.x) >> 4;
    const int ngroups = (gridDim.x * blockDim.x) >> 4;

    for (int row = group; row < B; row += ngroups) {
        const int a = idx[row];   // broadcast within the 16-lane group

        const float4 se =
            reinterpret_cast<const float4*>(state + (size_t)row * 64)[lane16];
        const float4 ne =
            reinterpret_cast<const float4*>(node + (size_t)a * 64)[lane16];

        // s = dot(state_row, W4) : partial per lane, then 16-lane reduce.
        float s = se.x * w4.x + se.y * w4.y + se.z * w4.z + se.w * w4.w;
        #pragma unroll
        for (int o = 1; o < 16; o <<= 1) s += __shfl_xor(s, o);

        // q = sum_e relu(node_row[e] * s) * W5[e]
        float q = fmaxf(ne.x * s, 0.f) * w5.x
                + fmaxf(ne.y * s, 0.f) * w5.y
                + fmaxf(ne.z * s, 0.f) * w5.z
                + fmaxf(ne.w * s, 0.f) * w5.w;
        #pragma unroll
        for (int o = 1; o < 16; o <<= 1) q += __shfl_xor(q, o);

        if (lane16 == 0) out[row] = q;
    }
}

extern "C" void kernel_launch(void* const* d_in, const int* in_sizes, int n_in,
                              void* d_out, int out_size, void* d_ws, size_t ws_size,
                              hipStream_t stream) {
    const int*   idx   = (const int*)  d_in[0];  // actions_idx     [B]
    const float* node  = (const float*)d_in[1];  // node_embedding  [N,64]
    const float* state = (const float*)d_in[2];  // state_embedding [B,64]
    const float* W4    = (const float*)d_in[3];  // [64,1]
    const float* W5    = (const float*)d_in[4];  // [64,1]
    float*       out   = (float*)d_out;          // [B,1]

    const int B = in_sizes[0];

    const int block  = 256;
    const int blocks = 2048;  // grid-stride; 2048*256/16 = 32768 row-groups
    Decoding_43404939493634_kernel<<<blocks, block, 0, stream>>>(
        idx, node, state, W4, W5, out, B);
}